// Round 5
// baseline (873.781 us; speedup 1.0000x reference)
//
#include <hip/hip_runtime.h>
#include <math.h>

#define Bc   8
#define Nc   2048
#define Mc   1024
#define Kc   64
#define Fc   64
#define C0c  67
#define C1c  64
#define C2c  128
#define NGRP (Bc*Mc)     /* 8192 */
#define R2c  0.04f
#define EPSc 1e-5f
#define NBLK 2048
#define GPB  (NGRP/NBLK) /* 4 groups per block for k_l2 — measured optimum */
#define FPSB 8           /* fps blocks inside fused kernel */

/* workspace layout (bytes). First WS_ZERO_QW*8 bytes are zeroed by k_clear. */
#define WS_PUB      0         /* ull[8*256] packed fps publications (16384 B) */
#define WS_CNT      16384     /* int cnt_total */
#define WS_P1PART   16640     /* float[2][8][64]  BN1 staged partials (4096 B) */
#define WS_P2PART   20736     /* float[2][8][128] BN2 staged partials (8192 B) */
#define WS_ZERO_QW  3616      /* zero first 28928 B */
#define WS_CNTARR   32768     /* int[8192] */
#define WS_NBR      65536     /* int[8192*64] (2 MB) */
#define WS_QWS      2162688   /* float[8192*4] */
#define WS_MAXV     2293760   /* float[8192*128] (4 MB) -> ends 6488064 (budget 11.47 MB) */

// numpy-matching squared distance: individually rounded mul/add, no FMA contraction
__device__ __forceinline__ float d2nf(float dx, float dy, float dz) {
  return __fadd_rn(__fadd_rn(__fmul_rn(dx,dx), __fmul_rn(dy,dy)), __fmul_rn(dz,dz));
}

// acc[0..3] += h * w  (4 FMAs)
__device__ __forceinline__ void fma4(float* a, float h, const float4 w) {
  a[0] = fmaf(h, w.x, a[0]); a[1] = fmaf(h, w.y, a[1]);
  a[2] = fmaf(h, w.z, a[2]); a[3] = fmaf(h, w.w, a[3]);
}

// ---- DPP wave64 max reduction (VALU latency, NOT LDS-crossbar like shfl) ----
template<int CTRL>
__device__ __forceinline__ float dpp_maxf(float x) {
  const int o = __builtin_amdgcn_update_dpp(0, __float_as_int(x), CTRL, 0xf, 0xf, true);
  return fmaxf(x, __int_as_float(o));
}
__device__ __forceinline__ float wave_max64(float x) {
  x = dpp_maxf<0x111>(x);   // row_shr:1
  x = dpp_maxf<0x112>(x);   // row_shr:2
  x = dpp_maxf<0x114>(x);   // row_shr:4
  x = dpp_maxf<0x118>(x);   // row_shr:8
  x = dpp_maxf<0x142>(x);   // row_bcast:15
  x = dpp_maxf<0x143>(x);   // row_bcast:31 -> lane63 = full 64-lane max
  return __int_as_float(__builtin_amdgcn_readlane(__float_as_int(x), 63));
}

// Shared memory union: fps path (tiny) vs worker path (~19.2 KB).
union FusedSh {
  struct {
    __align__(16) float sV[2][4];
    __align__(16) float sI[2][4];
    __align__(16) float sX[2][4];
    __align__(16) float sY[2][4];
    __align__(16) float sZ[2][4];
    __align__(16) int   tags[2][4];   // per-parity per-wave step tags (spin handshake)
  } f;
  struct {
    __align__(16) float inb[Kc][68];   // 17408 B
    int   sc[256];                     // ball scan
    int   snbr[Kc];                    // local copy of nbr for immediate l1 gather
    int   sli;                         // broadcast of polled fps index
    float sred[C1c], sqred[C1c];
  } w;
};

// zeroes pub words, cnt_total, staged BN partials each launch
// (stream-ordered before k_fused -> no init race; graph replays safe).
__global__ __launch_bounds__(256) void k_clear(unsigned long long* __restrict__ ws0) {
  for (int i = blockIdx.x*256 + threadIdx.x; i < WS_ZERO_QW; i += gridDim.x*256)
    ws0[i] = 0ull;
}

// ---------------- Fused kernel: FPS (blocks 0..7) + ball+l1stats workers ----------------
// Round-5 change (single mechanism): the FPS loop's per-step __syncthreads() is replaced
// by a double-buffered LDS tag handshake (payload write -> threadfence_block -> tag store;
// readers spin on 4 relaxed tag loads). Theory: the barrier's full lgkmcnt/vmcnt drain +
// s_barrier was the unexplained ~600cy of the 1310cy/step; values/order are byte-identical.
// Protocol safety: parity double-buffer; a wave reaches step s+2 (same parity) only after
// all tags==s+1, which requires every wave to have finished READING step s. Tags zeroed at
// entry + one initial __syncthreads() kills cross-launch staleness.
__global__ __launch_bounds__(256, 4) void k_fused(
    const float* __restrict__ pos, const float* __restrict__ x,
    const float* __restrict__ W1, const float* __restrict__ b1,
    unsigned long long* __restrict__ pub64,
    int* __restrict__ nbr, int* __restrict__ cntarr, float* __restrict__ q_ws,
    int* __restrict__ cnt_total,
    float* __restrict__ out_pos, float* __restrict__ out_batch, float* __restrict__ out_idx,
    float* __restrict__ p1part, int nworkers)
{
  __shared__ FusedSh sh;
  const int t = threadIdx.x;

  if (blockIdx.x < FPSB) {
    // ================= FPS path: proven structure + packed publication + tag handshake =================
    __builtin_amdgcn_s_setprio(3);       // protect the latency chain from co-resident workers
    const int b = blockIdx.x;
    const float* pb = pos + (size_t)b*Nc*3;
    const int base = t*8;
    float X[8],Y[8],Z[8],Mv[8];
    {   // 24 floats/thread, 16B-aligned (96B stride) -> 6 float4 loads
      float4 buf[6];
      const float4* src = (const float4*)(pb + (size_t)base*3);
      #pragma unroll
      for (int ii=0; ii<6; ii++) buf[ii] = src[ii];
      const float* pf = (const float*)buf;
      #pragma unroll
      for (int i=0;i<8;i++){ X[i]=pf[i*3+0]; Y[i]=pf[i*3+1]; Z[i]=pf[i*3+2]; }
    }
    if (t < 8) ((int*)sh.f.tags)[t] = 0;   // zero both parities' tags
    const float q0x=pb[0], q0y=pb[1], q0z=pb[2];
    #pragma unroll
    for (int i=0;i<8;i++) Mv[i] = d2nf(X[i]-q0x, Y[i]-q0y, Z[i]-q0z);
    float m = fmaxf(fmaxf(fmaxf(Mv[0],Mv[1]), fmaxf(Mv[2],Mv[3])),
                    fmaxf(fmaxf(Mv[4],Mv[5]), fmaxf(Mv[6],Mv[7])));
    const int wid = t >> 6, lane = t & 63;
    __syncthreads();                       // ONE barrier: tags visible before any handshake
    // 4 indices (11 bits each) per 64-bit publication word, bit63 = ready.
    // Slot sel%4==0 of word 0 is the fixed start index 0 (pubacc starts at 0).
    unsigned long long pubacc = 0ull;
    for (int sel = 1; sel < Mc; sel++) {
      const float v = wave_max64(m);
      const unsigned long long bal = __ballot(m == v);
      const int l0 = __ffsll(bal) - 1;
      int fpos = 7;
      #pragma unroll
      for (int i=6;i>=0;i--) fpos = (Mv[i]==v) ? i : fpos;
      float sx=X[7], sy=Y[7], sz=Z[7];
      #pragma unroll
      for (int i=6;i>=0;i--){ const bool p=(Mv[i]==v); sx=p?X[i]:sx; sy=p?Y[i]:sy; sz=p?Z[i]:sz; }
      const int par = sel & 1;                 // double-buffered slots
      if (lane == l0) {
        sh.f.sV[par][wid] = v;
        sh.f.sI[par][wid] = __int_as_float(base + fpos);
        sh.f.sX[par][wid] = sx; sh.f.sY[par][wid] = sy; sh.f.sZ[par][wid] = sz;
      }
      __threadfence_block();                   // drain this wave's payload LDS writes
      if (lane == l0)
        __hip_atomic_store(&sh.f.tags[par][wid], sel,
                           __ATOMIC_RELAXED, __HIP_MEMORY_SCOPE_WORKGROUP);
      {   // spin until all 4 wave slots of this parity reach sel (expected 1-2 polls)
        int a0, a1, a2, a3;
        do {
          a0 = __hip_atomic_load(&sh.f.tags[par][0], __ATOMIC_RELAXED, __HIP_MEMORY_SCOPE_WORKGROUP);
          a1 = __hip_atomic_load(&sh.f.tags[par][1], __ATOMIC_RELAXED, __HIP_MEMORY_SCOPE_WORKGROUP);
          a2 = __hip_atomic_load(&sh.f.tags[par][2], __ATOMIC_RELAXED, __HIP_MEMORY_SCOPE_WORKGROUP);
          a3 = __hip_atomic_load(&sh.f.tags[par][3], __ATOMIC_RELAXED, __HIP_MEMORY_SCOPE_WORKGROUP);
        } while ((a0 < sel) | (a1 < sel) | (a2 < sel) | (a3 < sel));
      }
      __threadfence_block();                   // order payload reads after tag confirm
      const float4 Vv = *(const float4*)sh.f.sV[par];
      const float4 Iv = *(const float4*)sh.f.sI[par];
      const float4 Xv = *(const float4*)sh.f.sX[par];
      const float4 Yv = *(const float4*)sh.f.sY[par];
      const float4 Zv = *(const float4*)sh.f.sZ[par];
      const float bm = fmaxf(fmaxf(Vv.x,Vv.y), fmaxf(Vv.z,Vv.w));
      int fi = __float_as_int(Iv.w);           // descending chain -> lowest wave wins ties
      float nqx=Xv.w, nqy=Yv.w, nqz=Zv.w;
      if (Vv.z == bm) { fi=__float_as_int(Iv.z); nqx=Xv.z; nqy=Yv.z; nqz=Zv.z; }
      if (Vv.y == bm) { fi=__float_as_int(Iv.y); nqx=Xv.y; nqy=Yv.y; nqz=Zv.y; }
      if (Vv.x == bm) { fi=__float_as_int(Iv.x); nqx=Xv.x; nqy=Yv.x; nqz=Zv.x; }
      pubacc |= ((unsigned long long)(unsigned)fi) << (11*(sel&3));
      if ((sel & 3) == 3) {
        if (t == 0)
          __hip_atomic_store(&pub64[b*256 + (sel>>2)], pubacc | (1ull<<63),
                             __ATOMIC_RELAXED, __HIP_MEMORY_SCOPE_AGENT);
        pubacc = 0ull;
      }
      #pragma unroll
      for (int i=0;i<8;i++) {
        const float d = d2nf(X[i]-nqx, Y[i]-nqy, Z[i]-nqz);
        Mv[i] = fminf(Mv[i], d);
      }
      m = fmaxf(fmaxf(fmaxf(Mv[0],Mv[1]), fmaxf(Mv[2],Mv[3])),
                fmaxf(fmaxf(Mv[4],Mv[5]), fmaxf(Mv[6],Mv[7])));
    }
    // Mc-1 = 1023 -> last publish at sel=1023 (1023&3==3): all words complete.
  } else {
    // ================= worker path: poll -> ball -> l1stats partial, s-major order =================
    const int w = blockIdx.x - FPSB;
    const int c0 = (t & 15) * 4, kg = t >> 4;  // l1 GEMM mapping (k = kg*4+j, c = c0..c0+3)
    const int gk = t >> 2, gq = t & 3;         // gather mapping
    const float4 b1q = *(const float4*)(b1 + c0);
    float ssum0=0,ssum1=0,ssum2=0,ssum3=0, ssq0=0,ssq1=0,ssq2=0,ssq3=0;
    for (int kk = w; kk < NGRP; kk += nworkers) {
      const int s = kk >> 3, b = kk & 7;       // s-major: ready-time increases with kk
      const int g = b*Mc + s;
      if (t == 0) {                            // single poller per block; flag+data in one word
        unsigned long long v;
        while (!((v = __hip_atomic_load(&pub64[b*256 + (s>>2)],
                                        __ATOMIC_RELAXED, __HIP_MEMORY_SCOPE_AGENT)) >> 63))
          __builtin_amdgcn_s_sleep(8);
        sh.w.sli = (int)((v >> (11*(s&3))) & 0x7FFull);
      }
      __syncthreads();
      const int li = sh.w.sli;
      const float* pb = pos + (size_t)b*Nc*3;
      const float qx = pb[li*3+0], qy = pb[li*3+1], qz = pb[li*3+2];
      // ---- ball (first-K by index), proven body ----
      const int base = t*8;
      unsigned mask = 0;
      #pragma unroll
      for (int i=0;i<8;i++){
        const int j = base+i;
        const float d = d2nf(pb[j*3+0]-qx, pb[j*3+1]-qy, pb[j*3+2]-qz);
        if (d <= R2c) mask |= (1u<<i);
      }
      const int c = __popc(mask);
      sh.w.sc[t] = c; __syncthreads();
      for (int off=1; off<256; off<<=1) {      // inclusive Hillis-Steele scan
        const int add = (t>=off) ? sh.w.sc[t-off] : 0;
        __syncthreads();
        sh.w.sc[t] += add;
        __syncthreads();
      }
      const int total = sh.w.sc[255];
      int slot = sh.w.sc[t] - c;               // exclusive prefix
      #pragma unroll
      for (int i=0;i<8;i++){
        if (mask & (1u<<i)) {
          if (slot < Kc) { nbr[(size_t)g*Kc + slot] = base+i; sh.w.snbr[slot] = base+i; }
          slot++;
        }
      }
      const int cnt = total < Kc ? total : Kc;
      if (t == 0) {
        cntarr[g] = cnt;
        atomicAdd(cnt_total, cnt);
        q_ws[g*4+0]=qx; q_ws[g*4+1]=qy; q_ws[g*4+2]=qz;
        out_pos[g*3+0]=qx; out_pos[g*3+1]=qy; out_pos[g*3+2]=qz;
        out_batch[g] = (float)b;
        out_idx[g]   = (float)(b*Nc + li);
      }
      __syncthreads();                         // snbr ready
      // ---- l1stats body (proven): gather -> GEMM -> masked relu stats ----
      {
        float4* dst = (float4*)(&sh.w.inb[gk][0]);
        if (gk < cnt) {
          const int idx = sh.w.snbr[gk];
          const float4* xr = (const float4*)(x + ((size_t)b*Nc + idx)*Fc);
          #pragma unroll
          for (int ii=0; ii<4; ii++) dst[gq*4+ii] = xr[gq*4+ii];
          if (gq == 0) {
            const float* pp = pos + ((size_t)b*Nc + idx)*3;
            sh.w.inb[gk][64] = pp[0] - qx;
            sh.w.inb[gk][65] = pp[1] - qy;
            sh.w.inb[gk][66] = pp[2] - qz;
            sh.w.inb[gk][67] = 0.f;
          }
        } else {
          const float4 z4 = make_float4(0.f,0.f,0.f,0.f);
          #pragma unroll
          for (int ii=0; ii<4; ii++) dst[gq*4+ii] = z4;
          if (gq == 0) { sh.w.inb[gk][64]=0.f; sh.w.inb[gk][65]=0.f; sh.w.inb[gk][66]=0.f; sh.w.inb[gk][67]=0.f; }
        }
      }
      __syncthreads();
      float acc[4][4];
      #pragma unroll
      for (int j=0;j<4;j++){acc[j][0]=0.f;acc[j][1]=0.f;acc[j][2]=0.f;acc[j][3]=0.f;}
      for (int cq = 0; cq < 16; cq++) {        // cc quads 0..63: b128 activation reads
        const int cc = cq*4;
        const float4 h0 = *(const float4*)(&sh.w.inb[kg*4+0][cc]);
        const float4 h1 = *(const float4*)(&sh.w.inb[kg*4+1][cc]);
        const float4 h2 = *(const float4*)(&sh.w.inb[kg*4+2][cc]);
        const float4 h3 = *(const float4*)(&sh.w.inb[kg*4+3][cc]);
        const float4 w0 = *(const float4*)(W1 + (cc+0)*C1c + c0);
        const float4 w1 = *(const float4*)(W1 + (cc+1)*C1c + c0);
        const float4 w2 = *(const float4*)(W1 + (cc+2)*C1c + c0);
        const float4 w3 = *(const float4*)(W1 + (cc+3)*C1c + c0);
        fma4(acc[0], h0.x, w0); fma4(acc[1], h1.x, w0); fma4(acc[2], h2.x, w0); fma4(acc[3], h3.x, w0);
        fma4(acc[0], h0.y, w1); fma4(acc[1], h1.y, w1); fma4(acc[2], h2.y, w1); fma4(acc[3], h3.y, w1);
        fma4(acc[0], h0.z, w2); fma4(acc[1], h1.z, w2); fma4(acc[2], h2.z, w2); fma4(acc[3], h3.z, w2);
        fma4(acc[0], h0.w, w3); fma4(acc[1], h1.w, w3); fma4(acc[2], h2.w, w3); fma4(acc[3], h3.w, w3);
      }
      #pragma unroll
      for (int cc = 64; cc < C0c; cc++) {      // tail 64..66 scalar
        const float4 wv = *(const float4*)(W1 + cc*C1c + c0);
        #pragma unroll
        for (int j=0;j<4;j++) fma4(acc[j], sh.w.inb[kg*4 + j][cc], wv);
      }
      #pragma unroll
      for (int j=0;j<4;j++) {
        const int k2 = kg*4 + j;
        if (k2 < cnt) {
          const float r0 = fmaxf(acc[j][0] + b1q.x, 0.f);
          const float r1 = fmaxf(acc[j][1] + b1q.y, 0.f);
          const float r2 = fmaxf(acc[j][2] + b1q.z, 0.f);
          const float r3 = fmaxf(acc[j][3] + b1q.w, 0.f);
          ssum0 += r0; ssq0 += r0*r0;
          ssum1 += r1; ssq1 += r1*r1;
          ssum2 += r2; ssq2 += r2*r2;
          ssum3 += r3; ssq3 += r3*r3;
        }
      }
      __syncthreads();                         // protect inb/sc before next group
    }
    // block partial -> 8 staged global rows (<=127-way contention; replaces p1sum+k_fin1)
    if (t < C1c) { sh.w.sred[t]=0.f; sh.w.sqred[t]=0.f; }
    __syncthreads();
    atomicAdd(&sh.w.sred[c0+0], ssum0); atomicAdd(&sh.w.sqred[c0+0], ssq0);
    atomicAdd(&sh.w.sred[c0+1], ssum1); atomicAdd(&sh.w.sqred[c0+1], ssq1);
    atomicAdd(&sh.w.sred[c0+2], ssum2); atomicAdd(&sh.w.sqred[c0+2], ssq2);
    atomicAdd(&sh.w.sred[c0+3], ssum3); atomicAdd(&sh.w.sqred[c0+3], ssq3);
    __syncthreads();
    if (t < C1c) {
      atomicAdd(p1part + (w & 7)*C1c + t,             sh.w.sred[t]);
      atomicAdd(p1part + 8*C1c + (w & 7)*C1c + t,     sh.w.sqred[t]);
    }
  }
}

// ---------------- Kernel 5: BN1-affine prologue, recompute r1, layer2, masked max + staged stats2 ----------------
__global__ __launch_bounds__(256) void k_l2(const float* __restrict__ x, const float* __restrict__ pos,
                                            const float* __restrict__ W1, const float* __restrict__ b1,
                                            const float* __restrict__ W2, const float* __restrict__ b2,
                                            const int* __restrict__ nbr, const int* __restrict__ cntarr,
                                            const float* __restrict__ q_ws,
                                            const float* __restrict__ p1part, const int* __restrict__ cnt_total,
                                            const float* __restrict__ g1, const float* __restrict__ be1,
                                            float* __restrict__ p2part, float* __restrict__ maxv) {
  __shared__ __align__(16) float inb[Kc][68];
  __shared__ __align__(16) float h1b[Kc][68];
  __shared__ float redmax[8][C2c];
  __shared__ float sred[C2c], sqred[C2c];
  __shared__ __align__(16) float affs[2][C1c];
  const int t = threadIdx.x;
  // BN1 finalize from 8 staged rows (replaces k_fin1; kernel boundary = visibility)
  if (t < C1c) {
    float s = 0.f, sq = 0.f;
    #pragma unroll
    for (int r = 0; r < 8; r++) { s += p1part[r*C1c + t]; sq += p1part[8*C1c + r*C1c + t]; }
    const float cntf = (float)(*cnt_total);
    const float mean = s / cntf;
    const float var = fmaxf(sq / cntf - mean*mean, 0.f);
    const float a = g1[t] / sqrtf(var + EPSc);
    affs[0][t] = a;
    affs[1][t] = be1[t] - mean * a;
  }
  __syncthreads();
  const int c0a = (t & 15) * 4, kga = t >> 4;
  const int c0b = (t & 31) * 4, kgb = t >> 5;
  const float4 b1q = *(const float4*)(b1 + c0a);
  const float4 a1q = *(const float4*)(&affs[0][c0a]);
  const float4 c1q = *(const float4*)(&affs[1][c0a]);
  const float4 b2q = *(const float4*)(b2 + c0b);
  float ssum0=0,ssum1=0,ssum2=0,ssum3=0, ssq0=0,ssq1=0,ssq2=0,ssq3=0;
  const int gk = t >> 2, gq = t & 3;
  for (int gi = 0; gi < GPB; gi++) {
    const int g = blockIdx.x * GPB + gi;
    const int cnt = cntarr[g];
    const int b = g >> 10;
    {   // gather
      float4* dst = (float4*)(&inb[gk][0]);
      if (gk < cnt) {
        const int idx = nbr[(size_t)g*Kc + gk];
        const float4* xr = (const float4*)(x + ((size_t)b*Nc + idx)*Fc);
        #pragma unroll
        for (int ii=0; ii<4; ii++) dst[gq*4+ii] = xr[gq*4+ii];
        if (gq == 0) {
          const float* pp = pos + ((size_t)b*Nc + idx)*3;
          inb[gk][64] = pp[0] - q_ws[g*4+0];
          inb[gk][65] = pp[1] - q_ws[g*4+1];
          inb[gk][66] = pp[2] - q_ws[g*4+2];
          inb[gk][67] = 0.f;
        }
      } else {
        const float4 z4 = make_float4(0.f,0.f,0.f,0.f);
        #pragma unroll
        for (int ii=0; ii<4; ii++) dst[gq*4+ii] = z4;
        if (gq == 0) { inb[gk][64]=0.f; inb[gk][65]=0.f; inb[gk][66]=0.f; inb[gk][67]=0.f; }
      }
    }
    __syncthreads();
    {   // phase A: h1 = a1*relu(in@W1+b1)+c1 -> LDS
      float acc[4][4];
      #pragma unroll
      for (int j=0;j<4;j++){acc[j][0]=0.f;acc[j][1]=0.f;acc[j][2]=0.f;acc[j][3]=0.f;}
      for (int cq = 0; cq < 16; cq++) {
        const int cc = cq*4;
        const float4 h0 = *(const float4*)(&inb[kga*4+0][cc]);
        const float4 h1 = *(const float4*)(&inb[kga*4+1][cc]);
        const float4 h2 = *(const float4*)(&inb[kga*4+2][cc]);
        const float4 h3 = *(const float4*)(&inb[kga*4+3][cc]);
        const float4 w0 = *(const float4*)(W1 + (cc+0)*C1c + c0a);
        const float4 w1 = *(const float4*)(W1 + (cc+1)*C1c + c0a);
        const float4 w2 = *(const float4*)(W1 + (cc+2)*C1c + c0a);
        const float4 w3 = *(const float4*)(W1 + (cc+3)*C1c + c0a);
        fma4(acc[0], h0.x, w0); fma4(acc[1], h1.x, w0); fma4(acc[2], h2.x, w0); fma4(acc[3], h3.x, w0);
        fma4(acc[0], h0.y, w1); fma4(acc[1], h1.y, w1); fma4(acc[2], h2.y, w1); fma4(acc[3], h3.y, w1);
        fma4(acc[0], h0.z, w2); fma4(acc[1], h1.z, w2); fma4(acc[2], h2.z, w2); fma4(acc[3], h3.z, w2);
        fma4(acc[0], h0.w, w3); fma4(acc[1], h1.w, w3); fma4(acc[2], h2.w, w3); fma4(acc[3], h3.w, w3);
      }
      #pragma unroll
      for (int cc = 64; cc < C0c; cc++) {
        const float4 w = *(const float4*)(W1 + cc*C1c + c0a);
        #pragma unroll
        for (int j=0;j<4;j++) fma4(acc[j], inb[kga*4 + j][cc], w);
      }
      #pragma unroll
      for (int j=0;j<4;j++) {
        const int k = kga*4 + j;
        float4 h;
        h.x = a1q.x * fmaxf(acc[j][0] + b1q.x, 0.f) + c1q.x;
        h.y = a1q.y * fmaxf(acc[j][1] + b1q.y, 0.f) + c1q.y;
        h.z = a1q.z * fmaxf(acc[j][2] + b1q.z, 0.f) + c1q.z;
        h.w = a1q.w * fmaxf(acc[j][3] + b1q.w, 0.f) + c1q.w;
        *(float4*)(&h1b[k][c0a]) = h;
      }
    }
    __syncthreads();
    {   // phase B: r2 = relu(h1@W2+b2); masked stats + max over k
      float acc[8][4];
      #pragma unroll
      for (int j=0;j<8;j++){acc[j][0]=0.f;acc[j][1]=0.f;acc[j][2]=0.f;acc[j][3]=0.f;}
      for (int cq = 0; cq < 16; cq++) {
        const int cc = cq*4;
        float4 hb[8];
        #pragma unroll
        for (int j=0;j<8;j++) hb[j] = *(const float4*)(&h1b[kgb*8+j][cc]);
        const float4 w0 = *(const float4*)(W2 + (cc+0)*C2c + c0b);
        const float4 w1 = *(const float4*)(W2 + (cc+1)*C2c + c0b);
        const float4 w2 = *(const float4*)(W2 + (cc+2)*C2c + c0b);
        const float4 w3 = *(const float4*)(W2 + (cc+3)*C2c + c0b);
        #pragma unroll
        for (int j=0;j<8;j++) {
          fma4(acc[j], hb[j].x, w0);
          fma4(acc[j], hb[j].y, w1);
          fma4(acc[j], hb[j].z, w2);
          fma4(acc[j], hb[j].w, w3);
        }
      }
      float lx0=-INFINITY,lx1=-INFINITY,lx2=-INFINITY,lx3=-INFINITY;
      #pragma unroll
      for (int j=0;j<8;j++) {
        const int k = kgb*8 + j;
        if (k < cnt) {
          const float r0 = fmaxf(acc[j][0] + b2q.x, 0.f);
          const float r1 = fmaxf(acc[j][1] + b2q.y, 0.f);
          const float r2 = fmaxf(acc[j][2] + b2q.z, 0.f);
          const float r3 = fmaxf(acc[j][3] + b2q.w, 0.f);
          ssum0 += r0; ssq0 += r0*r0;
          ssum1 += r1; ssq1 += r1*r1;
          ssum2 += r2; ssq2 += r2*r2;
          ssum3 += r3; ssq3 += r3*r3;
          lx0 = fmaxf(lx0, r0);
          lx1 = fmaxf(lx1, r1);
          lx2 = fmaxf(lx2, r2);
          lx3 = fmaxf(lx3, r3);
        }
      }
      redmax[kgb][c0b+0]=lx0; redmax[kgb][c0b+1]=lx1; redmax[kgb][c0b+2]=lx2; redmax[kgb][c0b+3]=lx3;
    }
    __syncthreads();
    if (t < C2c) {
      float mx = redmax[0][t];
      #pragma unroll
      for (int w=1; w<8; w++) mx = fmaxf(mx, redmax[w][t]);
      maxv[(size_t)g*C2c + t] = mx;
    }
    __syncthreads();
  }
  // block partial -> 8 staged global rows (256-way contention; replaces p2sum+k_fin2)
  if (t < C2c) { sred[t] = 0.f; sqred[t] = 0.f; }
  __syncthreads();
  atomicAdd(&sred[c0b+0], ssum0); atomicAdd(&sqred[c0b+0], ssq0);
  atomicAdd(&sred[c0b+1], ssum1); atomicAdd(&sqred[c0b+1], ssq1);
  atomicAdd(&sred[c0b+2], ssum2); atomicAdd(&sqred[c0b+2], ssq2);
  atomicAdd(&sred[c0b+3], ssum3); atomicAdd(&sqred[c0b+3], ssq3);
  __syncthreads();
  if (t < C2c) {
    atomicAdd(p2part + (blockIdx.x & 7)*C2c + t,           sred[t]);
    atomicAdd(p2part + 8*C2c + (blockIdx.x & 7)*C2c + t,   sqred[t]);
  }
}

// ---------------- Kernel 7: BN2-affine prologue + x_out = a2*max + c2 (BN2 commutes with max; a2>0) ----------------
__global__ __launch_bounds__(256) void k_out(const float* __restrict__ maxv,
                                             const float* __restrict__ p2part, const int* __restrict__ cnt_total,
                                             const float* __restrict__ g2, const float* __restrict__ be2,
                                             float* __restrict__ xout) {
  __shared__ float affs[2][C2c];
  const int t = threadIdx.x;
  if (t < C2c) {
    float s = 0.f, sq = 0.f;
    #pragma unroll
    for (int r = 0; r < 8; r++) { s += p2part[r*C2c + t]; sq += p2part[8*C2c + r*C2c + t]; }
    const float cntf = (float)(*cnt_total);
    const float mean = s / cntf;
    const float var = fmaxf(sq / cntf - mean*mean, 0.f);
    const float a = g2[t] / sqrtf(var + EPSc);
    affs[0][t] = a;
    affs[1][t] = be2[t] - mean * a;
  }
  __syncthreads();
  const int i = blockIdx.x*256 + t;
  const int c = i & (C2c-1);
  xout[i] = affs[0][c] * maxv[i] + affs[1][c];
}

extern "C" void kernel_launch(void* const* d_in, const int* in_sizes, int n_in,
                              void* d_out, int out_size, void* d_ws, size_t ws_size,
                              hipStream_t stream) {
  (void)in_sizes; (void)n_in; (void)out_size; (void)ws_size;
  const float* x   = (const float*)d_in[0];
  const float* pos = (const float*)d_in[1];
  const float* W1  = (const float*)d_in[3];
  const float* b1  = (const float*)d_in[4];
  const float* g1  = (const float*)d_in[5];
  const float* be1 = (const float*)d_in[6];
  const float* W2  = (const float*)d_in[7];
  const float* b2  = (const float*)d_in[8];
  const float* g2  = (const float*)d_in[9];
  const float* be2 = (const float*)d_in[10];

  char* ws = (char*)d_ws;
  unsigned long long* pub64 = (unsigned long long*)(ws + WS_PUB);
  int*   cnt_total = (int*)  (ws + WS_CNT);
  float* p1part    = (float*)(ws + WS_P1PART);
  float* p2part    = (float*)(ws + WS_P2PART);
  int*   cntarr    = (int*)  (ws + WS_CNTARR);
  int*   nbr       = (int*)  (ws + WS_NBR);
  float* q_ws      = (float*)(ws + WS_QWS);
  float* maxv      = (float*)(ws + WS_MAXV);

  float* xout      = (float*)d_out;            // [8192*128]
  float* out_pos   = xout + (size_t)NGRP*C2c;  // [8192*3]
  float* out_batch = out_pos + (size_t)NGRP*3; // [8192]
  float* out_idx   = out_batch + NGRP;         // [8192]

  // Grid sizing: occupancy * CU count == guaranteed co-resident capacity.
  // Host-side queries only (legal under graph capture); cached in statics.
  static int g_W = 0;
  if (g_W == 0) {
    int nb = 0;
    if (hipOccupancyMaxActiveBlocksPerMultiprocessor(&nb, reinterpret_cast<const void*>(k_fused),
                                                     256, 0) != hipSuccess || nb < 1) nb = 4;
    hipDeviceProp_t prop;
    int mp = 256;
    if (hipGetDeviceProperties(&prop, 0) == hipSuccess && prop.multiProcessorCount > 0)
      mp = prop.multiProcessorCount;
    int wv = nb * mp - FPSB;
    if (wv < 8) wv = 8;
    g_W = wv;
  }
  const int nw = g_W;

  k_clear<<<8, 256, 0, stream>>>((unsigned long long*)ws);
  k_fused<<<FPSB + nw, 256, 0, stream>>>(pos, x, W1, b1, pub64, nbr, cntarr, q_ws,
                                         cnt_total, out_pos, out_batch, out_idx,
                                         p1part, nw);
  k_l2<<<NBLK, 256, 0, stream>>>(x, pos, W1, b1, W2, b2, nbr, cntarr, q_ws,
                                 p1part, cnt_total, g1, be1, p2part, maxv);
  k_out<<<(NGRP*C2c)/256, 256, 0, stream>>>(maxv, p2part, cnt_total, g2, be2, xout);
}

// Round 6
// 778.485 us; speedup vs baseline: 1.1224x; 1.1224x over previous
//
#include <hip/hip_runtime.h>
#include <math.h>

#define Bc   8
#define Nc   2048
#define Mc   1024
#define Kc   64
#define Fc   64
#define C0c  67
#define C1c  64
#define C2c  128
#define NGRP (Bc*Mc)     /* 8192 */
#define R2c  0.04f
#define EPSc 1e-5f
#define NBLK 2048
#define GPB  (NGRP/NBLK) /* 4 groups per block for k_l2 — measured optimum */
#define FPSB 8           /* fps blocks inside fused kernel */

/* workspace layout (bytes). First WS_ZERO_QW*8 bytes are zeroed by k_clear. */
#define WS_PUB      0         /* ull[8*256] packed fps publications (16384 B) */
#define WS_CNT      16384     /* int cnt_total */
#define WS_P1PART   16640     /* float[2][8][64]  BN1 staged partials (4096 B) */
#define WS_P2PART   20736     /* float[2][8][128] BN2 staged partials (8192 B) */
#define WS_ZERO_QW  3616      /* zero first 28928 B */
#define WS_CNTARR   32768     /* int[8192] */
#define WS_NBR      65536     /* int[8192*64] (2 MB) */
#define WS_QWS      2162688   /* float[8192*4] */
#define WS_MAXV     2293760   /* float[8192*128] (4 MB) -> ends 6488064 (budget 11.47 MB) */

// numpy-matching squared distance: individually rounded mul/add, no FMA contraction
__device__ __forceinline__ float d2nf(float dx, float dy, float dz) {
  return __fadd_rn(__fadd_rn(__fmul_rn(dx,dx), __fmul_rn(dy,dy)), __fmul_rn(dz,dz));
}

// acc[0..3] += h * w  (4 FMAs)
__device__ __forceinline__ void fma4(float* a, float h, const float4 w) {
  a[0] = fmaf(h, w.x, a[0]); a[1] = fmaf(h, w.y, a[1]);
  a[2] = fmaf(h, w.z, a[2]); a[3] = fmaf(h, w.w, a[3]);
}

// ---- DPP wave64 max reduction (VALU latency, NOT LDS-crossbar like shfl) ----
template<int CTRL>
__device__ __forceinline__ float dpp_maxf(float x) {
  const int o = __builtin_amdgcn_update_dpp(0, __float_as_int(x), CTRL, 0xf, 0xf, true);
  return fmaxf(x, __int_as_float(o));
}
__device__ __forceinline__ float wave_max64(float x) {
  x = dpp_maxf<0x111>(x);   // row_shr:1
  x = dpp_maxf<0x112>(x);   // row_shr:2
  x = dpp_maxf<0x114>(x);   // row_shr:4
  x = dpp_maxf<0x118>(x);   // row_shr:8
  x = dpp_maxf<0x142>(x);   // row_bcast:15
  x = dpp_maxf<0x143>(x);   // row_bcast:31 -> lane63 = full 64-lane max
  return __int_as_float(__builtin_amdgcn_readlane(__float_as_int(x), 63));
}

// Shared memory union: fps path (tiny) vs worker path (~19.2 KB).
// Round-5 lesson: LDS tag-handshake instead of __syncthreads REGRESSED (630us + 31ms
// outlier) — s_barrier is cheap; the FPS step is latency-bound in DPP+LDS-rt+update.
union FusedSh {
  struct {
    __align__(16) float sV[2][4];
    __align__(16) float sI[2][4];
    __align__(16) float sX[2][4];
    __align__(16) float sY[2][4];
    __align__(16) float sZ[2][4];
  } f;
  struct {
    __align__(16) float inb[Kc][68];   // 17408 B
    int   sc[256];                     // ball scan
    int   snbr[Kc];                    // local copy of nbr for immediate l1 gather
    int   sli;                         // broadcast of polled fps index
    float sred[C1c], sqred[C1c];
  } w;
};

// zeroes pub words, cnt_total, staged BN partials each launch
// (stream-ordered before k_fused -> no init race; graph replays safe).
__global__ __launch_bounds__(256) void k_clear(unsigned long long* __restrict__ ws0) {
  for (int i = blockIdx.x*256 + threadIdx.x; i < WS_ZERO_QW; i += gridDim.x*256)
    ws0[i] = 0ull;
}

// ---------------- Fused kernel: FPS (blocks 0..7) + ball+l1stats workers (round-2/4 proven, 546us) ----------------
// REGULAR launch. Deadlock-freedom by construction: __launch_bounds__(256,4) pins
// occupancy at 4 blocks/CU (VGPR<=128 is plenty for this kernel's ~60; LDS 19.2KB
// would allow 8), and the host sizes the grid to occupancy*CUs, so grid <= co-resident
// capacity -> every block, producer and consumer alike, is resident regardless of order.
__global__ __launch_bounds__(256, 4) void k_fused(
    const float* __restrict__ pos, const float* __restrict__ x,
    const float* __restrict__ W1, const float* __restrict__ b1,
    unsigned long long* __restrict__ pub64,
    int* __restrict__ nbr, int* __restrict__ cntarr, float* __restrict__ q_ws,
    int* __restrict__ cnt_total,
    float* __restrict__ out_pos, float* __restrict__ out_batch, float* __restrict__ out_idx,
    float* __restrict__ p1part, int nworkers)
{
  __shared__ FusedSh sh;
  const int t = threadIdx.x;

  if (blockIdx.x < FPSB) {
    // ================= FPS path: proven 556us structure, + packed publication =================
    __builtin_amdgcn_s_setprio(3);       // protect the latency chain from co-resident workers
    const int b = blockIdx.x;
    const float* pb = pos + (size_t)b*Nc*3;
    const int base = t*8;
    float X[8],Y[8],Z[8],Mv[8];
    {   // 24 floats/thread, 16B-aligned (96B stride) -> 6 float4 loads
      float4 buf[6];
      const float4* src = (const float4*)(pb + (size_t)base*3);
      #pragma unroll
      for (int ii=0; ii<6; ii++) buf[ii] = src[ii];
      const float* pf = (const float*)buf;
      #pragma unroll
      for (int i=0;i<8;i++){ X[i]=pf[i*3+0]; Y[i]=pf[i*3+1]; Z[i]=pf[i*3+2]; }
    }
    const float q0x=pb[0], q0y=pb[1], q0z=pb[2];
    #pragma unroll
    for (int i=0;i<8;i++) Mv[i] = d2nf(X[i]-q0x, Y[i]-q0y, Z[i]-q0z);
    float m = fmaxf(fmaxf(fmaxf(Mv[0],Mv[1]), fmaxf(Mv[2],Mv[3])),
                    fmaxf(fmaxf(Mv[4],Mv[5]), fmaxf(Mv[6],Mv[7])));
    const int wid = t >> 6, lane = t & 63;
    // 4 indices (11 bits each) per 64-bit publication word, bit63 = ready.
    // Slot sel%4==0 of word 0 is the fixed start index 0 (pubacc starts at 0).
    // Unroll-by-4: makes the 11*(sel&3) shifts compile-time constants and the
    // publication branch static (position 3 of each body) — less loop overhead
    // in the issue stream; semantics byte-identical.
    unsigned long long pubacc = 0ull;
    #pragma unroll 4
    for (int sel = 1; sel < Mc; sel++) {
      const float v = wave_max64(m);
      const unsigned long long bal = __ballot(m == v);
      const int l0 = __ffsll(bal) - 1;
      int fpos = 7;
      #pragma unroll
      for (int i=6;i>=0;i--) fpos = (Mv[i]==v) ? i : fpos;
      float sx=X[7], sy=Y[7], sz=Z[7];
      #pragma unroll
      for (int i=6;i>=0;i--){ const bool p=(Mv[i]==v); sx=p?X[i]:sx; sy=p?Y[i]:sy; sz=p?Z[i]:sz; }
      const int par = sel & 1;                 // double-buffered slots: 1 barrier/step
      if (lane == l0) {
        sh.f.sV[par][wid] = v;
        sh.f.sI[par][wid] = __int_as_float(base + fpos);
        sh.f.sX[par][wid] = sx; sh.f.sY[par][wid] = sy; sh.f.sZ[par][wid] = sz;
      }
      __syncthreads();
      const float4 Vv = *(const float4*)sh.f.sV[par];
      const float4 Iv = *(const float4*)sh.f.sI[par];
      const float4 Xv = *(const float4*)sh.f.sX[par];
      const float4 Yv = *(const float4*)sh.f.sY[par];
      const float4 Zv = *(const float4*)sh.f.sZ[par];
      const float bm = fmaxf(fmaxf(Vv.x,Vv.y), fmaxf(Vv.z,Vv.w));
      int fi = __float_as_int(Iv.w);           // descending chain -> lowest wave wins ties
      float nqx=Xv.w, nqy=Yv.w, nqz=Zv.w;
      if (Vv.z == bm) { fi=__float_as_int(Iv.z); nqx=Xv.z; nqy=Yv.z; nqz=Zv.z; }
      if (Vv.y == bm) { fi=__float_as_int(Iv.y); nqx=Xv.y; nqy=Yv.y; nqz=Zv.y; }
      if (Vv.x == bm) { fi=__float_as_int(Iv.x); nqx=Xv.x; nqy=Yv.x; nqz=Zv.x; }
      pubacc |= ((unsigned long long)(unsigned)fi) << (11*(sel&3));
      if ((sel & 3) == 3) {
        if (t == 0)
          __hip_atomic_store(&pub64[b*256 + (sel>>2)], pubacc | (1ull<<63),
                             __ATOMIC_RELAXED, __HIP_MEMORY_SCOPE_AGENT);
        pubacc = 0ull;
      }
      #pragma unroll
      for (int i=0;i<8;i++) {
        const float d = d2nf(X[i]-nqx, Y[i]-nqy, Z[i]-nqz);
        Mv[i] = fminf(Mv[i], d);
      }
      m = fmaxf(fmaxf(fmaxf(Mv[0],Mv[1]), fmaxf(Mv[2],Mv[3])),
                fmaxf(fmaxf(Mv[4],Mv[5]), fmaxf(Mv[6],Mv[7])));
    }
    // Mc-1 = 1023 -> last publish at sel=1023 (1023&3==3): all words complete.
  } else {
    // ================= worker path: poll -> ball -> l1stats partial, s-major order =================
    const int w = blockIdx.x - FPSB;
    const int c0 = (t & 15) * 4, kg = t >> 4;  // l1 GEMM mapping (k = kg*4+j, c = c0..c0+3)
    const int gk = t >> 2, gq = t & 3;         // gather mapping
    const float4 b1q = *(const float4*)(b1 + c0);
    float ssum0=0,ssum1=0,ssum2=0,ssum3=0, ssq0=0,ssq1=0,ssq2=0,ssq3=0;
    for (int kk = w; kk < NGRP; kk += nworkers) {
      const int s = kk >> 3, b = kk & 7;       // s-major: ready-time increases with kk
      const int g = b*Mc + s;
      if (t == 0) {                            // single poller per block; flag+data in one word
        unsigned long long v;
        while (!((v = __hip_atomic_load(&pub64[b*256 + (s>>2)],
                                        __ATOMIC_RELAXED, __HIP_MEMORY_SCOPE_AGENT)) >> 63))
          __builtin_amdgcn_s_sleep(8);
        sh.w.sli = (int)((v >> (11*(s&3))) & 0x7FFull);
      }
      __syncthreads();
      const int li = sh.w.sli;
      const float* pb = pos + (size_t)b*Nc*3;
      const float qx = pb[li*3+0], qy = pb[li*3+1], qz = pb[li*3+2];
      // ---- ball (first-K by index), proven body ----
      const int base = t*8;
      unsigned mask = 0;
      #pragma unroll
      for (int i=0;i<8;i++){
        const int j = base+i;
        const float d = d2nf(pb[j*3+0]-qx, pb[j*3+1]-qy, pb[j*3+2]-qz);
        if (d <= R2c) mask |= (1u<<i);
      }
      const int c = __popc(mask);
      sh.w.sc[t] = c; __syncthreads();
      for (int off=1; off<256; off<<=1) {      // inclusive Hillis-Steele scan
        const int add = (t>=off) ? sh.w.sc[t-off] : 0;
        __syncthreads();
        sh.w.sc[t] += add;
        __syncthreads();
      }
      const int total = sh.w.sc[255];
      int slot = sh.w.sc[t] - c;               // exclusive prefix
      #pragma unroll
      for (int i=0;i<8;i++){
        if (mask & (1u<<i)) {
          if (slot < Kc) { nbr[(size_t)g*Kc + slot] = base+i; sh.w.snbr[slot] = base+i; }
          slot++;
        }
      }
      const int cnt = total < Kc ? total : Kc;
      if (t == 0) {
        cntarr[g] = cnt;
        atomicAdd(cnt_total, cnt);
        q_ws[g*4+0]=qx; q_ws[g*4+1]=qy; q_ws[g*4+2]=qz;
        out_pos[g*3+0]=qx; out_pos[g*3+1]=qy; out_pos[g*3+2]=qz;
        out_batch[g] = (float)b;
        out_idx[g]   = (float)(b*Nc + li);
      }
      __syncthreads();                         // snbr ready
      // ---- l1stats body (proven): gather -> GEMM -> masked relu stats ----
      {
        float4* dst = (float4*)(&sh.w.inb[gk][0]);
        if (gk < cnt) {
          const int idx = sh.w.snbr[gk];
          const float4* xr = (const float4*)(x + ((size_t)b*Nc + idx)*Fc);
          #pragma unroll
          for (int ii=0; ii<4; ii++) dst[gq*4+ii] = xr[gq*4+ii];
          if (gq == 0) {
            const float* pp = pos + ((size_t)b*Nc + idx)*3;
            sh.w.inb[gk][64] = pp[0] - qx;
            sh.w.inb[gk][65] = pp[1] - qy;
            sh.w.inb[gk][66] = pp[2] - qz;
            sh.w.inb[gk][67] = 0.f;
          }
        } else {
          const float4 z4 = make_float4(0.f,0.f,0.f,0.f);
          #pragma unroll
          for (int ii=0; ii<4; ii++) dst[gq*4+ii] = z4;
          if (gq == 0) { sh.w.inb[gk][64]=0.f; sh.w.inb[gk][65]=0.f; sh.w.inb[gk][66]=0.f; sh.w.inb[gk][67]=0.f; }
        }
      }
      __syncthreads();
      float acc[4][4];
      #pragma unroll
      for (int j=0;j<4;j++){acc[j][0]=0.f;acc[j][1]=0.f;acc[j][2]=0.f;acc[j][3]=0.f;}
      for (int cq = 0; cq < 16; cq++) {        // cc quads 0..63: b128 activation reads
        const int cc = cq*4;
        const float4 h0 = *(const float4*)(&sh.w.inb[kg*4+0][cc]);
        const float4 h1 = *(const float4*)(&sh.w.inb[kg*4+1][cc]);
        const float4 h2 = *(const float4*)(&sh.w.inb[kg*4+2][cc]);
        const float4 h3 = *(const float4*)(&sh.w.inb[kg*4+3][cc]);
        const float4 w0 = *(const float4*)(W1 + (cc+0)*C1c + c0);
        const float4 w1 = *(const float4*)(W1 + (cc+1)*C1c + c0);
        const float4 w2 = *(const float4*)(W1 + (cc+2)*C1c + c0);
        const float4 w3 = *(const float4*)(W1 + (cc+3)*C1c + c0);
        fma4(acc[0], h0.x, w0); fma4(acc[1], h1.x, w0); fma4(acc[2], h2.x, w0); fma4(acc[3], h3.x, w0);
        fma4(acc[0], h0.y, w1); fma4(acc[1], h1.y, w1); fma4(acc[2], h2.y, w1); fma4(acc[3], h3.y, w1);
        fma4(acc[0], h0.z, w2); fma4(acc[1], h1.z, w2); fma4(acc[2], h2.z, w2); fma4(acc[3], h3.z, w2);
        fma4(acc[0], h0.w, w3); fma4(acc[1], h1.w, w3); fma4(acc[2], h2.w, w3); fma4(acc[3], h3.w, w3);
      }
      #pragma unroll
      for (int cc = 64; cc < C0c; cc++) {      // tail 64..66 scalar
        const float4 wv = *(const float4*)(W1 + cc*C1c + c0);
        #pragma unroll
        for (int j=0;j<4;j++) fma4(acc[j], sh.w.inb[kg*4 + j][cc], wv);
      }
      #pragma unroll
      for (int j=0;j<4;j++) {
        const int k2 = kg*4 + j;
        if (k2 < cnt) {
          const float r0 = fmaxf(acc[j][0] + b1q.x, 0.f);
          const float r1 = fmaxf(acc[j][1] + b1q.y, 0.f);
          const float r2 = fmaxf(acc[j][2] + b1q.z, 0.f);
          const float r3 = fmaxf(acc[j][3] + b1q.w, 0.f);
          ssum0 += r0; ssq0 += r0*r0;
          ssum1 += r1; ssq1 += r1*r1;
          ssum2 += r2; ssq2 += r2*r2;
          ssum3 += r3; ssq3 += r3*r3;
        }
      }
      __syncthreads();                         // protect inb/sc before next group
    }
    // block partial -> 8 staged global rows (<=127-way contention; replaces p1sum+k_fin1)
    if (t < C1c) { sh.w.sred[t]=0.f; sh.w.sqred[t]=0.f; }
    __syncthreads();
    atomicAdd(&sh.w.sred[c0+0], ssum0); atomicAdd(&sh.w.sqred[c0+0], ssq0);
    atomicAdd(&sh.w.sred[c0+1], ssum1); atomicAdd(&sh.w.sqred[c0+1], ssq1);
    atomicAdd(&sh.w.sred[c0+2], ssum2); atomicAdd(&sh.w.sqred[c0+2], ssq2);
    atomicAdd(&sh.w.sred[c0+3], ssum3); atomicAdd(&sh.w.sqred[c0+3], ssq3);
    __syncthreads();
    if (t < C1c) {
      atomicAdd(p1part + (w & 7)*C1c + t,             sh.w.sred[t]);
      atomicAdd(p1part + 8*C1c + (w & 7)*C1c + t,     sh.w.sqred[t]);
    }
  }
}

// ---------------- Kernel 5: BN1-affine prologue, recompute r1, layer2, masked max + staged stats2 ----------------
__global__ __launch_bounds__(256) void k_l2(const float* __restrict__ x, const float* __restrict__ pos,
                                            const float* __restrict__ W1, const float* __restrict__ b1,
                                            const float* __restrict__ W2, const float* __restrict__ b2,
                                            const int* __restrict__ nbr, const int* __restrict__ cntarr,
                                            const float* __restrict__ q_ws,
                                            const float* __restrict__ p1part, const int* __restrict__ cnt_total,
                                            const float* __restrict__ g1, const float* __restrict__ be1,
                                            float* __restrict__ p2part, float* __restrict__ maxv) {
  __shared__ __align__(16) float inb[Kc][68];
  __shared__ __align__(16) float h1b[Kc][68];
  __shared__ float redmax[8][C2c];
  __shared__ float sred[C2c], sqred[C2c];
  __shared__ __align__(16) float affs[2][C1c];
  const int t = threadIdx.x;
  // BN1 finalize from 8 staged rows (replaces k_fin1; kernel boundary = visibility)
  if (t < C1c) {
    float s = 0.f, sq = 0.f;
    #pragma unroll
    for (int r = 0; r < 8; r++) { s += p1part[r*C1c + t]; sq += p1part[8*C1c + r*C1c + t]; }
    const float cntf = (float)(*cnt_total);
    const float mean = s / cntf;
    const float var = fmaxf(sq / cntf - mean*mean, 0.f);
    const float a = g1[t] / sqrtf(var + EPSc);
    affs[0][t] = a;
    affs[1][t] = be1[t] - mean * a;
  }
  __syncthreads();
  const int c0a = (t & 15) * 4, kga = t >> 4;
  const int c0b = (t & 31) * 4, kgb = t >> 5;
  const float4 b1q = *(const float4*)(b1 + c0a);
  const float4 a1q = *(const float4*)(&affs[0][c0a]);
  const float4 c1q = *(const float4*)(&affs[1][c0a]);
  const float4 b2q = *(const float4*)(b2 + c0b);
  float ssum0=0,ssum1=0,ssum2=0,ssum3=0, ssq0=0,ssq1=0,ssq2=0,ssq3=0;
  const int gk = t >> 2, gq = t & 3;
  for (int gi = 0; gi < GPB; gi++) {
    const int g = blockIdx.x * GPB + gi;
    const int cnt = cntarr[g];
    const int b = g >> 10;
    {   // gather
      float4* dst = (float4*)(&inb[gk][0]);
      if (gk < cnt) {
        const int idx = nbr[(size_t)g*Kc + gk];
        const float4* xr = (const float4*)(x + ((size_t)b*Nc + idx)*Fc);
        #pragma unroll
        for (int ii=0; ii<4; ii++) dst[gq*4+ii] = xr[gq*4+ii];
        if (gq == 0) {
          const float* pp = pos + ((size_t)b*Nc + idx)*3;
          inb[gk][64] = pp[0] - q_ws[g*4+0];
          inb[gk][65] = pp[1] - q_ws[g*4+1];
          inb[gk][66] = pp[2] - q_ws[g*4+2];
          inb[gk][67] = 0.f;
        }
      } else {
        const float4 z4 = make_float4(0.f,0.f,0.f,0.f);
        #pragma unroll
        for (int ii=0; ii<4; ii++) dst[gq*4+ii] = z4;
        if (gq == 0) { inb[gk][64]=0.f; inb[gk][65]=0.f; inb[gk][66]=0.f; inb[gk][67]=0.f; }
      }
    }
    __syncthreads();
    {   // phase A: h1 = a1*relu(in@W1+b1)+c1 -> LDS
      float acc[4][4];
      #pragma unroll
      for (int j=0;j<4;j++){acc[j][0]=0.f;acc[j][1]=0.f;acc[j][2]=0.f;acc[j][3]=0.f;}
      for (int cq = 0; cq < 16; cq++) {
        const int cc = cq*4;
        const float4 h0 = *(const float4*)(&inb[kga*4+0][cc]);
        const float4 h1 = *(const float4*)(&inb[kga*4+1][cc]);
        const float4 h2 = *(const float4*)(&inb[kga*4+2][cc]);
        const float4 h3 = *(const float4*)(&inb[kga*4+3][cc]);
        const float4 w0 = *(const float4*)(W1 + (cc+0)*C1c + c0a);
        const float4 w1 = *(const float4*)(W1 + (cc+1)*C1c + c0a);
        const float4 w2 = *(const float4*)(W1 + (cc+2)*C1c + c0a);
        const float4 w3 = *(const float4*)(W1 + (cc+3)*C1c + c0a);
        fma4(acc[0], h0.x, w0); fma4(acc[1], h1.x, w0); fma4(acc[2], h2.x, w0); fma4(acc[3], h3.x, w0);
        fma4(acc[0], h0.y, w1); fma4(acc[1], h1.y, w1); fma4(acc[2], h2.y, w1); fma4(acc[3], h3.y, w1);
        fma4(acc[0], h0.z, w2); fma4(acc[1], h1.z, w2); fma4(acc[2], h2.z, w2); fma4(acc[3], h3.z, w2);
        fma4(acc[0], h0.w, w3); fma4(acc[1], h1.w, w3); fma4(acc[2], h2.w, w3); fma4(acc[3], h3.w, w3);
      }
      #pragma unroll
      for (int cc = 64; cc < C0c; cc++) {
        const float4 w = *(const float4*)(W1 + cc*C1c + c0a);
        #pragma unroll
        for (int j=0;j<4;j++) fma4(acc[j], inb[kga*4 + j][cc], w);
      }
      #pragma unroll
      for (int j=0;j<4;j++) {
        const int k = kga*4 + j;
        float4 h;
        h.x = a1q.x * fmaxf(acc[j][0] + b1q.x, 0.f) + c1q.x;
        h.y = a1q.y * fmaxf(acc[j][1] + b1q.y, 0.f) + c1q.y;
        h.z = a1q.z * fmaxf(acc[j][2] + b1q.z, 0.f) + c1q.z;
        h.w = a1q.w * fmaxf(acc[j][3] + b1q.w, 0.f) + c1q.w;
        *(float4*)(&h1b[k][c0a]) = h;
      }
    }
    __syncthreads();
    {   // phase B: r2 = relu(h1@W2+b2); masked stats + max over k
      float acc[8][4];
      #pragma unroll
      for (int j=0;j<8;j++){acc[j][0]=0.f;acc[j][1]=0.f;acc[j][2]=0.f;acc[j][3]=0.f;}
      for (int cq = 0; cq < 16; cq++) {
        const int cc = cq*4;
        float4 hb[8];
        #pragma unroll
        for (int j=0;j<8;j++) hb[j] = *(const float4*)(&h1b[kgb*8+j][cc]);
        const float4 w0 = *(const float4*)(W2 + (cc+0)*C2c + c0b);
        const float4 w1 = *(const float4*)(W2 + (cc+1)*C2c + c0b);
        const float4 w2 = *(const float4*)(W2 + (cc+2)*C2c + c0b);
        const float4 w3 = *(const float4*)(W2 + (cc+3)*C2c + c0b);
        #pragma unroll
        for (int j=0;j<8;j++) {
          fma4(acc[j], hb[j].x, w0);
          fma4(acc[j], hb[j].y, w1);
          fma4(acc[j], hb[j].z, w2);
          fma4(acc[j], hb[j].w, w3);
        }
      }
      float lx0=-INFINITY,lx1=-INFINITY,lx2=-INFINITY,lx3=-INFINITY;
      #pragma unroll
      for (int j=0;j<8;j++) {
        const int k = kgb*8 + j;
        if (k < cnt) {
          const float r0 = fmaxf(acc[j][0] + b2q.x, 0.f);
          const float r1 = fmaxf(acc[j][1] + b2q.y, 0.f);
          const float r2 = fmaxf(acc[j][2] + b2q.z, 0.f);
          const float r3 = fmaxf(acc[j][3] + b2q.w, 0.f);
          ssum0 += r0; ssq0 += r0*r0;
          ssum1 += r1; ssq1 += r1*r1;
          ssum2 += r2; ssq2 += r2*r2;
          ssum3 += r3; ssq3 += r3*r3;
          lx0 = fmaxf(lx0, r0);
          lx1 = fmaxf(lx1, r1);
          lx2 = fmaxf(lx2, r2);
          lx3 = fmaxf(lx3, r3);
        }
      }
      redmax[kgb][c0b+0]=lx0; redmax[kgb][c0b+1]=lx1; redmax[kgb][c0b+2]=lx2; redmax[kgb][c0b+3]=lx3;
    }
    __syncthreads();
    if (t < C2c) {
      float mx = redmax[0][t];
      #pragma unroll
      for (int w=1; w<8; w++) mx = fmaxf(mx, redmax[w][t]);
      maxv[(size_t)g*C2c + t] = mx;
    }
    __syncthreads();
  }
  // block partial -> 8 staged global rows (256-way contention; replaces p2sum+k_fin2)
  if (t < C2c) { sred[t] = 0.f; sqred[t] = 0.f; }
  __syncthreads();
  atomicAdd(&sred[c0b+0], ssum0); atomicAdd(&sqred[c0b+0], ssq0);
  atomicAdd(&sred[c0b+1], ssum1); atomicAdd(&sqred[c0b+1], ssq1);
  atomicAdd(&sred[c0b+2], ssum2); atomicAdd(&sqred[c0b+2], ssq2);
  atomicAdd(&sred[c0b+3], ssum3); atomicAdd(&sqred[c0b+3], ssq3);
  __syncthreads();
  if (t < C2c) {
    atomicAdd(p2part + (blockIdx.x & 7)*C2c + t,           sred[t]);
    atomicAdd(p2part + 8*C2c + (blockIdx.x & 7)*C2c + t,   sqred[t]);
  }
}

// ---------------- Kernel 7: BN2-affine prologue + x_out = a2*max + c2 (BN2 commutes with max; a2>0) ----------------
__global__ __launch_bounds__(256) void k_out(const float* __restrict__ maxv,
                                             const float* __restrict__ p2part, const int* __restrict__ cnt_total,
                                             const float* __restrict__ g2, const float* __restrict__ be2,
                                             float* __restrict__ xout) {
  __shared__ float affs[2][C2c];
  const int t = threadIdx.x;
  if (t < C2c) {
    float s = 0.f, sq = 0.f;
    #pragma unroll
    for (int r = 0; r < 8; r++) { s += p2part[r*C2c + t]; sq += p2part[8*C2c + r*C2c + t]; }
    const float cntf = (float)(*cnt_total);
    const float mean = s / cntf;
    const float var = fmaxf(sq / cntf - mean*mean, 0.f);
    const float a = g2[t] / sqrtf(var + EPSc);
    affs[0][t] = a;
    affs[1][t] = be2[t] - mean * a;
  }
  __syncthreads();
  const int i = blockIdx.x*256 + t;
  const int c = i & (C2c-1);
  xout[i] = affs[0][c] * maxv[i] + affs[1][c];
}

extern "C" void kernel_launch(void* const* d_in, const int* in_sizes, int n_in,
                              void* d_out, int out_size, void* d_ws, size_t ws_size,
                              hipStream_t stream) {
  (void)in_sizes; (void)n_in; (void)out_size; (void)ws_size;
  const float* x   = (const float*)d_in[0];
  const float* pos = (const float*)d_in[1];
  const float* W1  = (const float*)d_in[3];
  const float* b1  = (const float*)d_in[4];
  const float* g1  = (const float*)d_in[5];
  const float* be1 = (const float*)d_in[6];
  const float* W2  = (const float*)d_in[7];
  const float* b2  = (const float*)d_in[8];
  const float* g2  = (const float*)d_in[9];
  const float* be2 = (const float*)d_in[10];

  char* ws = (char*)d_ws;
  unsigned long long* pub64 = (unsigned long long*)(ws + WS_PUB);
  int*   cnt_total = (int*)  (ws + WS_CNT);
  float* p1part    = (float*)(ws + WS_P1PART);
  float* p2part    = (float*)(ws + WS_P2PART);
  int*   cntarr    = (int*)  (ws + WS_CNTARR);
  int*   nbr       = (int*)  (ws + WS_NBR);
  float* q_ws      = (float*)(ws + WS_QWS);
  float* maxv      = (float*)(ws + WS_MAXV);

  float* xout      = (float*)d_out;            // [8192*128]
  float* out_pos   = xout + (size_t)NGRP*C2c;  // [8192*3]
  float* out_batch = out_pos + (size_t)NGRP*3; // [8192]
  float* out_idx   = out_batch + NGRP;         // [8192]

  // Grid sizing: occupancy * CU count == guaranteed co-resident capacity.
  // Host-side queries only (legal under graph capture); cached in statics.
  static int g_W = 0;
  if (g_W == 0) {
    int nb = 0;
    if (hipOccupancyMaxActiveBlocksPerMultiprocessor(&nb, reinterpret_cast<const void*>(k_fused),
                                                     256, 0) != hipSuccess || nb < 1) nb = 4;
    hipDeviceProp_t prop;
    int mp = 256;
    if (hipGetDeviceProperties(&prop, 0) == hipSuccess && prop.multiProcessorCount > 0)
      mp = prop.multiProcessorCount;
    int wv = nb * mp - FPSB;
    if (wv < 8) wv = 8;
    g_W = wv;
  }
  const int nw = g_W;

  k_clear<<<8, 256, 0, stream>>>((unsigned long long*)ws);
  k_fused<<<FPSB + nw, 256, 0, stream>>>(pos, x, W1, b1, pub64, nbr, cntarr, q_ws,
                                         cnt_total, out_pos, out_batch, out_idx,
                                         p1part, nw);
  k_l2<<<NBLK, 256, 0, stream>>>(x, pos, W1, b1, W2, b2, nbr, cntarr, q_ws,
                                 p1part, cnt_total, g1, be1, p2part, maxv);
  k_out<<<(NGRP*C2c)/256, 256, 0, stream>>>(maxv, p2part, cnt_total, g2, be2, xout);
}